// Round 1
// baseline (2895.386 us; speedup 1.0000x reference)
//
#include <hip/hip_runtime.h>
#include <hip/hip_bf16.h>

// ---------------- types & helpers ----------------
typedef short short8 __attribute__((ext_vector_type(8)));
typedef float f32x4 __attribute__((ext_vector_type(4)));
static_assert(sizeof(short8) == 16, "short8 must be 16B");

#define DEVFN static __device__ __forceinline__

DEVFN unsigned short f2bf_rne(float f) {
    union { float f; unsigned u; } x; x.f = f;
    unsigned u = x.u + 0x7FFFu + ((x.u >> 16) & 1u);
    return (unsigned short)(u >> 16);
}
DEVFN float bf2f(unsigned short h) {
    union { unsigned u; float f; } x; x.u = ((unsigned)h) << 16;
    return x.f;
}
DEVFN void f2bf_split(float f, unsigned short& hi, unsigned short& lo) {
    hi = f2bf_rne(f);
    lo = f2bf_rne(f - bf2f(hi));
}
DEVFN void split8(const float4 a, const float4 b, short8& hi, short8& lo) {
    float v[8] = {a.x, a.y, a.z, a.w, b.x, b.y, b.z, b.w};
#pragma unroll
    for (int i = 0; i < 8; i++) {
        unsigned short h, l;
        f2bf_split(v[i], h, l);
        hi[i] = (short)h; lo[i] = (short)l;
    }
}
DEVFN f32x4 mfma16(short8 a, short8 b, f32x4 c) {
    return __builtin_amdgcn_mfma_f32_16x16x32_bf16(a, b, c, 0, 0, 0);
}
DEVFN float sigmoidf_(float x) { return 1.0f / (1.0f + expf(-x)); }

// ---------------- constants ----------------
#define BB 16
#define TT 128
#define VV 32000
#define HH 512
#define LL 2
#define DDOCS 8
#define AH 256
#define EOS_ID 3
#define NROWS (BB * TT)       // 2048 GEMM rows
#define NBLKS 250             // 32000/128 N panels

// workspace offsets
#define OFF_CTX      ((size_t)0x0)       // 64KB  ctx[B][L][H] f32
#define OFF_SCORES   ((size_t)0x10000)   // scores[B*D*L] f32
#define OFF_RAWID    ((size_t)0x11000)   // 2048 int
#define OFF_FE       ((size_t)0x13000)   // 16 int
#define OFF_BAR      ((size_t)0x14000)   // 128 u32 barrier counters (memset 0)
#define OFF_XTOP_HI  ((size_t)0x100000)  // 2048*512 u16
#define OFF_XTOP_LO  ((size_t)0x300000)
#define OFF_PM       ((size_t)0x500000)  // 2048*250 f32 partial max
#define OFF_PS       ((size_t)0x700000)  // partial sumexp
#define OFF_PI       ((size_t)0x900000)  // partial argmax (int)
#define OFF_FACTOR   ((size_t)0xB00000)  // 2048*250 f32

// d_out scratch (region dead before c1 writes probs over it)
#define DOFF_XEMB_HI ((size_t)0x0)        // 2048*512 u16
#define DOFF_XEMB_LO ((size_t)0x200000)
#define DOFF_H0_HI   ((size_t)0x400000)   // raw h0 per t
#define DOFF_H0_LO   ((size_t)0x600000)
#define DOFF_H0M_HI  ((size_t)0x800000)   // mixed h0, 129 slots
#define DOFF_H0M_LO  ((size_t)0xA80000)
#define DOFF_H1M_HI  ((size_t)0xD00000)
#define DOFF_H1M_LO  ((size_t)0xF80000)

// ---------------- K0a: attention scores ----------------
__global__ void k0a_scores(const float* __restrict__ emb, const float* __restrict__ W1,
                           const float* __restrict__ b1, const float* __restrict__ W2,
                           const float* __restrict__ b2, float* __restrict__ scores) {
    int bid = blockIdx.x;  // (b*8+d)*2+l, 256
    int tid = threadIdx.x;
    __shared__ float sv[HH];
    const float* v = emb + (size_t)bid * HH;
    sv[tid] = v[tid]; sv[tid + 256] = v[tid + 256];
    __syncthreads();
    const float4* w4 = (const float4*)(W1 + (size_t)tid * HH);
    float s = b1[tid];
#pragma unroll 8
    for (int k = 0; k < HH / 4; k++) {
        float4 w = w4[k];
        s += w.x * sv[4 * k] + w.y * sv[4 * k + 1] + w.z * sv[4 * k + 2] + w.w * sv[4 * k + 3];
    }
    float t = tanhf(s) * W2[tid];
    __shared__ float red[256];
    red[tid] = t; __syncthreads();
    for (int off = 128; off > 0; off >>= 1) {
        if (tid < off) red[tid] += red[tid + off];
        __syncthreads();
    }
    if (tid == 0) scores[bid] = red[0] + b2[0];
}

// ---------------- K0b: softmax over docs + context ----------------
__global__ void k0b_ctx(const float* __restrict__ emb, const float* __restrict__ scores,
                        float* __restrict__ ctx) {
    int bid = blockIdx.x;  // b*2+l, 32
    int b = bid >> 1, l = bid & 1;
    int tid = threadIdx.x;
    float sc[DDOCS];
    float mx = -1e30f;
#pragma unroll
    for (int d = 0; d < DDOCS; d++) { sc[d] = scores[(b * DDOCS + d) * LL + l]; mx = fmaxf(mx, sc[d]); }
    float sum = 0.f;
#pragma unroll
    for (int d = 0; d < DDOCS; d++) { sc[d] = expf(sc[d] - mx); sum += sc[d]; }
    float inv = 1.0f / sum;
    for (int h = tid; h < HH; h += 256) {
        float acc = 0.f;
#pragma unroll
        for (int d = 0; d < DDOCS; d++)
            acc += sc[d] * inv * emb[((size_t)(b * DDOCS + d) * LL + l) * HH + h];
        ctx[(size_t)(b * LL + l) * HH + h] = acc;
    }
}

// ---------------- K1: embedding gather -> bf16 hi/lo ----------------
__global__ void k1_embed(const int* __restrict__ init_input, const int* __restrict__ targets,
                         const float* __restrict__ embW,
                         unsigned short* __restrict__ xe_hi, unsigned short* __restrict__ xe_lo) {
    int r = blockIdx.x;  // t*16+b
    int t = r >> 4, b = r & 15;
    int tok = (t == 0) ? init_input[b] : targets[b * TT + (t - 1)];
    const float* src = embW + (size_t)tok * HH;
    int tid = threadIdx.x;
    for (int k = tid; k < HH; k += 256) {
        unsigned short hi, lo;
        f2bf_split(src[k], hi, lo);
        xe_hi[(size_t)r * HH + k] = hi;
        xe_lo[(size_t)r * HH + k] = lo;
    }
}

// ---------------- K1b: init mixed hidden slot0 ----------------
__global__ void k1b_init(const float* __restrict__ ctx, const float* __restrict__ init_hidden,
                         unsigned short* __restrict__ h0m_hi, unsigned short* __restrict__ h0m_lo,
                         unsigned short* __restrict__ h1m_hi, unsigned short* __restrict__ h1m_lo) {
    int i = blockIdx.x * 256 + threadIdx.x;  // 0..16383
    if (i >= LL * BB * HH) return;
    int h = i & (HH - 1); int b = (i >> 9) & 15; int l = i >> 13;
    float c = ctx[(size_t)(b * LL + l) * HH + h];
    float ih = init_hidden[(size_t)(b * LL + l) * HH + h];
    float m = 0.5f * c + 0.5f * ih;
    unsigned short hi, lo; f2bf_split(m, hi, lo);
    size_t o = (size_t)b * HH + h;  // slot 0
    if (l == 0) { h0m_hi[o] = hi; h0m_lo[o] = lo; }
    else        { h1m_hi[o] = hi; h1m_lo[o] = lo; }
}

// ---------------- K2: persistent pipelined LSTM ----------------
// 128 blocks: 0..63 layer0, 64..127 layer1 (one step behind). Weights in VGPRs.
__global__ void __launch_bounds__(256, 1) k2_lstm(
    const float* __restrict__ W_ih, const float* __restrict__ W_hh,
    const float* __restrict__ b_ih, const float* __restrict__ b_hh,
    const float* __restrict__ ctx, const float* __restrict__ init_cell,
    const unsigned short* __restrict__ xe_hi, const unsigned short* __restrict__ xe_lo,
    unsigned short* __restrict__ h0_hi, unsigned short* __restrict__ h0_lo,
    unsigned short* __restrict__ h0m_hi, unsigned short* __restrict__ h0m_lo,
    unsigned short* __restrict__ h1m_hi, unsigned short* __restrict__ h1m_lo,
    unsigned short* __restrict__ xtop_hi, unsigned short* __restrict__ xtop_lo,
    unsigned int* __restrict__ bar) {
    const int wg = blockIdx.x;
    const int layer = wg >> 6;
    const int j0 = (wg & 63) * 8;
    const int tid = threadIdx.x;
    const int wv = tid >> 6;
    const int lane = tid & 63;
    const int n16 = lane & 15, q = lane >> 4;
    const int klocal = (wv & 1) * 256 + q * 8;  // + ks*32 added per kstep

    // ---- load weight fragments into registers (bf16 hi/lo) ----
    short8 Wh[2][8], Wl[2][8];
    {
        const float* wb = (wv < 2) ? (W_ih + (size_t)layer * 2048 * 512)
                                   : (W_hh + (size_t)layer * 2048 * 512);
#pragma unroll
        for (int nt = 0; nt < 2; nt++) {
            int rl = nt * 16 + n16;
            int g = rl >> 3, j = rl & 7;
            int n = g * 512 + j0 + j;
#pragma unroll
            for (int ks = 0; ks < 8; ks++) {
                const float* src = wb + (size_t)n * 512 + klocal + ks * 32;
                float4 a = ((const float4*)src)[0];
                float4 b4 = ((const float4*)src)[1];
                split8(a, b4, Wh[nt][ks], Wl[nt][ks]);
            }
        }
    }
    // ---- reducer-thread persistent state ----
    int m_b = tid & 15, jj = tid >> 4;  // valid tid<128
    float ccell = 0.f, ctxv = 0.f, biasv[4] = {0, 0, 0, 0};
    if (tid < 128) {
#pragma unroll
        for (int g = 0; g < 4; g++) {
            int n = g * 512 + j0 + jj;
            biasv[g] = b_ih[layer * 2048 + n] + b_hh[layer * 2048 + n];
        }
        ccell = init_cell[(size_t)(m_b * LL + layer) * HH + j0 + jj];
        ctxv = ctx[(size_t)(m_b * LL + layer) * HH + j0 + jj];
    }

    __shared__ float part[4][32][16];  // [wave][row_local][batch]

    for (int r = 0; r <= TT; r++) {
        bool active = (layer == 0) ? (r < TT) : (r >= 1);
        int t = (layer == 0) ? r : (r - 1);
        if (active) {
            const unsigned short* xbase_hi;
            const unsigned short* xbase_lo;
            if (layer == 0) {
                xbase_hi = (wv < 2) ? (xe_hi + (size_t)t * 8192) : (h0m_hi + (size_t)t * 8192);
                xbase_lo = (wv < 2) ? (xe_lo + (size_t)t * 8192) : (h0m_lo + (size_t)t * 8192);
            } else {
                xbase_hi = (wv < 2) ? (h0_hi + (size_t)t * 8192) : (h1m_hi + (size_t)t * 8192);
                xbase_lo = (wv < 2) ? (h0_lo + (size_t)t * 8192) : (h1m_lo + (size_t)t * 8192);
            }
            const unsigned short* ah = xbase_hi + (size_t)n16 * 512 + klocal;
            const unsigned short* al = xbase_lo + (size_t)n16 * 512 + klocal;
            f32x4 acc0 = {0.f, 0.f, 0.f, 0.f}, acc1 = {0.f, 0.f, 0.f, 0.f};
#pragma unroll
            for (int ks = 0; ks < 8; ks++) {
                short8 Ah = *(const short8*)(ah + ks * 32);
                short8 Al = *(const short8*)(al + ks * 32);
                acc0 = mfma16(Ah, Wh[0][ks], acc0);
                acc0 = mfma16(Al, Wh[0][ks], acc0);
                acc0 = mfma16(Ah, Wl[0][ks], acc0);
                acc1 = mfma16(Ah, Wh[1][ks], acc1);
                acc1 = mfma16(Al, Wh[1][ks], acc1);
                acc1 = mfma16(Ah, Wl[1][ks], acc1);
            }
            // D[m=q*4+reg][col=n16] -> part[wv][rl][m]
#pragma unroll
            for (int reg = 0; reg < 4; reg++) {
                part[wv][n16][q * 4 + reg] = acc0[reg];
                part[wv][16 + n16][q * 4 + reg] = acc1[reg];
            }
            __syncthreads();
            if (tid < 128) {
                float gs[4];
#pragma unroll
                for (int g = 0; g < 4; g++) {
                    int rl = g * 8 + jj;
                    gs[g] = part[0][rl][m_b] + part[1][rl][m_b] + part[2][rl][m_b] +
                            part[3][rl][m_b] + biasv[g];
                }
                float ig = sigmoidf_(gs[0]), fg = sigmoidf_(gs[1]);
                float gg = tanhf(gs[2]), og = sigmoidf_(gs[3]);
                ccell = fg * ccell + ig * gg;
                float h = og * tanhf(ccell);
                float hm = 0.5f * ctxv + 0.5f * h;
                unsigned short hhi, hlo, mhi, mlo;
                f2bf_split(h, hhi, hlo);
                f2bf_split(hm, mhi, mlo);
                size_t o = ((size_t)t * 16 + m_b) * 512 + j0 + jj;
                size_t o2 = ((size_t)(t + 1) * 16 + m_b) * 512 + j0 + jj;
                if (layer == 0) {
                    h0_hi[o] = hhi; h0_lo[o] = hlo;
                    h0m_hi[o2] = mhi; h0m_lo[o2] = mlo;
                } else {
                    xtop_hi[o] = hhi; xtop_lo[o] = hlo;
                    h1m_hi[o2] = mhi; h1m_lo[o2] = mlo;
                }
            }
        }
        if (r < TT) {  // inter-block barrier (fresh counter per round)
            __syncthreads();
            if (tid == 0) {
                __threadfence();
                __hip_atomic_fetch_add(&bar[r], 1u, __ATOMIC_RELEASE, __HIP_MEMORY_SCOPE_AGENT);
                while (__hip_atomic_load(&bar[r], __ATOMIC_RELAXED, __HIP_MEMORY_SCOPE_AGENT) < 128u)
                    __builtin_amdgcn_s_sleep(2);
                __threadfence();
            }
            __syncthreads();
        }
    }
}

// ---------------- C1: logits GEMM (split-bf16 MFMA) + fused partial softmax ----------------
__global__ void __launch_bounds__(256, 2) c1_gemm(
    const unsigned short* __restrict__ xhi, const unsigned short* __restrict__ xlo,
    const float* __restrict__ Wout, const float* __restrict__ b_out,
    float* __restrict__ outp, float* __restrict__ pm, float* __restrict__ ps,
    int* __restrict__ pi) {
    const int M0 = blockIdx.x * 128;   // 16 M panels
    const int N0 = blockIdx.y * 128;   // 250 N panels
    const int tid = threadIdx.x;
    const int wv = tid >> 6;
    const int lane = tid & 63;
    const int n16 = lane & 15, q = lane >> 4;

    f32x4 acc[8][2];
#pragma unroll
    for (int mt = 0; mt < 8; mt++)
#pragma unroll
        for (int i = 0; i < 2; i++) acc[mt][i] = (f32x4){0.f, 0.f, 0.f, 0.f};

    for (int ks = 0; ks < 16; ks++) {
        short8 Bh[2], Bl[2];
#pragma unroll
        for (int i = 0; i < 2; i++) {
            int n = N0 + (wv * 2 + i) * 16 + n16;
            const float* src = Wout + (size_t)n * 512 + ks * 32 + q * 8;
            float4 f0 = ((const float4*)src)[0];
            float4 f1 = ((const float4*)src)[1];
            split8(f0, f1, Bh[i], Bl[i]);
        }
#pragma unroll
        for (int mt = 0; mt < 8; mt++) {
            size_t aoff = ((size_t)(M0 + mt * 16 + n16)) * 512 + ks * 32 + q * 8;
            short8 Ah = *(const short8*)(xhi + aoff);
            short8 Al = *(const short8*)(xlo + aoff);
#pragma unroll
            for (int i = 0; i < 2; i++) {
                acc[mt][i] = mfma16(Ah, Bh[i], acc[mt][i]);
                acc[mt][i] = mfma16(Al, Bh[i], acc[mt][i]);
                acc[mt][i] = mfma16(Ah, Bl[i], acc[mt][i]);
            }
        }
    }
    // epilogue: bias, per-row(128 col) max/argmax/sumexp, store exp(l - m_blk)
    int c0 = N0 + (wv * 2) * 16 + n16;
    int c1 = c0 + 16;
    float bo0 = b_out[c0], bo1 = b_out[c1];

    __shared__ float smax[4][128];
    __shared__ int sidx[4][128];
    __shared__ float ssum[4][128];
    __shared__ float fmax[128];
    __shared__ int fidx[128];

#pragma unroll
    for (int mt = 0; mt < 8; mt++) {
#pragma unroll
        for (int reg = 0; reg < 4; reg++) {
            float v0 = acc[mt][0][reg] + bo0;
            float v1 = acc[mt][1][reg] + bo1;
            acc[mt][0][reg] = v0; acc[mt][1][reg] = v1;
            float mv = v0; int mi = c0;
            if (v1 > mv) { mv = v1; mi = c1; }
#pragma unroll
            for (int d = 1; d < 16; d <<= 1) {
                float om = __shfl_xor(mv, d);
                int oi = __shfl_xor(mi, d);
                if (om > mv || (om == mv && oi < mi)) { mv = om; mi = oi; }
            }
            if (n16 == 0) {
                smax[wv][mt * 16 + q * 4 + reg] = mv;
                sidx[wv][mt * 16 + q * 4 + reg] = mi;
            }
        }
    }
    __syncthreads();
    if (tid < 128) {
        float M = smax[0][tid]; int I = sidx[0][tid];
#pragma unroll
        for (int w = 1; w < 4; w++) {
            float m2 = smax[w][tid]; int i2 = sidx[w][tid];
            if (m2 > M || (m2 == M && i2 < I)) { M = m2; I = i2; }
        }
        fmax[tid] = M; fidx[tid] = I;
    }
    __syncthreads();
#pragma unroll
    for (int mt = 0; mt < 8; mt++) {
#pragma unroll
        for (int reg = 0; reg < 4; reg++) {
            int row = mt * 16 + q * 4 + reg;
            float M = fmax[row];
            float e0 = __expf(acc[mt][0][reg] - M);
            float e1 = __expf(acc[mt][1][reg] - M);
            int rg = M0 + row;
            int t = rg >> 4, b = rg & 15;
            size_t base = ((size_t)b * TT + t) * VV;
            outp[base + c0] = e0;
            outp[base + c1] = e1;
            float s = e0 + e1;
#pragma unroll
            for (int d = 1; d < 16; d <<= 1) s += __shfl_xor(s, d);
            if (n16 == 0) ssum[wv][row] = s;
        }
    }
    __syncthreads();
    if (tid < 128) {
        float S = ssum[0][tid] + ssum[1][tid] + ssum[2][tid] + ssum[3][tid];
        size_t o = (size_t)(M0 + tid) * NBLKS + blockIdx.y;
        pm[o] = fmax[tid]; ps[o] = S; pi[o] = fidx[tid];
    }
}

// ---------------- C2: per-row stats + factors ----------------
__global__ void c2_rowstats(const float* __restrict__ pm, const float* __restrict__ ps,
                            const int* __restrict__ pi, float* __restrict__ factor,
                            int* __restrict__ raw_id) {
    int row = blockIdx.x;
    int tid = threadIdx.x;
    float mi = -1e30f, si = 0.f; int ii = 0x7FFFFFFF;
    if (tid < NBLKS) {
        size_t o = (size_t)row * NBLKS + tid;
        mi = pm[o]; si = ps[o]; ii = pi[o];
    }
    __shared__ float sm[256]; __shared__ int si_[256]; __shared__ float sv[256];
    sm[tid] = mi; si_[tid] = ii;
    __syncthreads();
    for (int off = 128; off > 0; off >>= 1) {
        if (tid < off) {
            float m2 = sm[tid + off]; int i2 = si_[tid + off];
            if (m2 > sm[tid] || (m2 == sm[tid] && i2 < si_[tid])) { sm[tid] = m2; si_[tid] = i2; }
        }
        __syncthreads();
    }
    float M = sm[0];
    float term = (tid < NBLKS) ? si * __expf(mi - M) : 0.f;
    sv[tid] = term;
    __syncthreads();
    for (int off = 128; off > 0; off >>= 1) {
        if (tid < off) sv[tid] += sv[tid + off];
        __syncthreads();
    }
    float S = sv[0];
    if (tid == 0) raw_id[row] = si_[0];
    if (tid < NBLKS) factor[(size_t)row * NBLKS + tid] = __expf(mi - M) / S;
}

// ---------------- C2b: eos scan + ids output ----------------
__global__ void c2b_ids(const int* __restrict__ raw_id, int* __restrict__ fe,
                        float* __restrict__ out_ids) {
    int tid = threadIdx.x;
    __shared__ int fes[BB];
    if (tid < BB) {
        int f = 1 << 30;
        for (int t = 0; t < TT; t++) {
            if (raw_id[t * 16 + tid] == EOS_ID) { f = t; break; }
        }
        fes[tid] = f;
        fe[tid] = f;
    }
    __syncthreads();
    for (int i = tid; i < NROWS; i += 256) {
        int b = i >> 7, t = i & 127;
        int id = (t > fes[b]) ? 0 : raw_id[t * 16 + b];
        out_ids[i] = (float)id;
    }
}

// ---------------- C3: in-place normalize / pad-mask ----------------
__global__ void c3_norm(float* __restrict__ outp, const float* __restrict__ factor,
                        const int* __restrict__ fe) {
    int rg = blockIdx.x;  // gemm row
    int t = rg >> 4, b = rg & 15;
    size_t base = ((size_t)b * TT + t) * VV;
    int tid = threadIdx.x;
    bool pad = t > fe[b];
    if (pad) {
        for (int i = tid; i < VV / 4; i += 256) {
            float4 v = {0.f, 0.f, 0.f, 0.f};
            if (i == 0) v.x = 1.0f;
            ((float4*)(outp + base))[i] = v;
        }
    } else {
        for (int i = tid; i < VV / 4; i += 256) {
            float4 p = ((float4*)(outp + base))[i];
            float f = factor[(size_t)rg * NBLKS + (i >> 5)];
            p.x *= f; p.y *= f; p.z *= f; p.w *= f;
            ((float4*)(outp + base))[i] = p;
        }
    }
}

// ---------------- launch ----------------
extern "C" void kernel_launch(void* const* d_in, const int* in_sizes, int n_in,
                              void* d_out, int out_size, void* d_ws, size_t ws_size,
                              hipStream_t stream) {
    const float* init_hidden = (const float*)d_in[0];
    const float* init_cell = (const float*)d_in[1];
    const int* init_input = (const int*)d_in[2];
    const int* targets = (const int*)d_in[3];
    const float* attend = (const float*)d_in[4];
    const float* embW = (const float*)d_in[5];
    const float* W_ih = (const float*)d_in[6];
    const float* W_hh = (const float*)d_in[7];
    const float* b_ih = (const float*)d_in[8];
    const float* b_hh = (const float*)d_in[9];
    const float* W_out = (const float*)d_in[10];
    const float* b_out = (const float*)d_in[11];
    const float* attn_W1 = (const float*)d_in[12];
    const float* attn_b1 = (const float*)d_in[13];
    const float* attn_W2 = (const float*)d_in[14];
    const float* attn_b2 = (const float*)d_in[15];

    char* ws = (char*)d_ws;
    float* ctx = (float*)(ws + OFF_CTX);
    float* scores = (float*)(ws + OFF_SCORES);
    int* raw_id = (int*)(ws + OFF_RAWID);
    int* fe = (int*)(ws + OFF_FE);
    unsigned int* bar = (unsigned int*)(ws + OFF_BAR);
    unsigned short* xtop_hi = (unsigned short*)(ws + OFF_XTOP_HI);
    unsigned short* xtop_lo = (unsigned short*)(ws + OFF_XTOP_LO);
    float* pm = (float*)(ws + OFF_PM);
    float* ps = (float*)(ws + OFF_PS);
    int* pi = (int*)(ws + OFF_PI);
    float* factor = (float*)(ws + OFF_FACTOR);

    char* dob = (char*)d_out;
    unsigned short* xe_hi = (unsigned short*)(dob + DOFF_XEMB_HI);
    unsigned short* xe_lo = (unsigned short*)(dob + DOFF_XEMB_LO);
    unsigned short* h0_hi = (unsigned short*)(dob + DOFF_H0_HI);
    unsigned short* h0_lo = (unsigned short*)(dob + DOFF_H0_LO);
    unsigned short* h0m_hi = (unsigned short*)(dob + DOFF_H0M_HI);
    unsigned short* h0m_lo = (unsigned short*)(dob + DOFF_H0M_LO);
    unsigned short* h1m_hi = (unsigned short*)(dob + DOFF_H1M_HI);
    unsigned short* h1m_lo = (unsigned short*)(dob + DOFF_H1M_LO);

    float* outp = (float*)d_out;
    float* out_ids = outp + (size_t)NROWS * VV;

    hipMemsetAsync(bar, 0, 128 * sizeof(unsigned int), stream);

    k0a_scores<<<256, 256, 0, stream>>>(attend, attn_W1, attn_b1, attn_W2, attn_b2, scores);
    k0b_ctx<<<32, 256, 0, stream>>>(attend, scores, ctx);
    k1_embed<<<NROWS, 256, 0, stream>>>(init_input, targets, embW, xe_hi, xe_lo);
    k1b_init<<<64, 256, 0, stream>>>(ctx, init_hidden, h0m_hi, h0m_lo, h1m_hi, h1m_lo);
    k2_lstm<<<128, 256, 0, stream>>>(W_ih, W_hh, b_ih, b_hh, ctx, init_cell,
                                     xe_hi, xe_lo, h0_hi, h0_lo, h0m_hi, h0m_lo,
                                     h1m_hi, h1m_lo, xtop_hi, xtop_lo, bar);
    c1_gemm<<<dim3(16, NBLKS), 256, 0, stream>>>(xtop_hi, xtop_lo, W_out, b_out,
                                                 outp, pm, ps, pi);
    c2_rowstats<<<NROWS, 256, 0, stream>>>(pm, ps, pi, factor, raw_id);
    c2b_ids<<<1, 256, 0, stream>>>(raw_id, fe, out_ids);
    c3_norm<<<NROWS, 256, 0, stream>>>(outp, factor, fe);
}

// Round 2
// 1928.284 us; speedup vs baseline: 1.5015x; 1.5015x over previous
//
#include <hip/hip_runtime.h>
#include <hip/hip_bf16.h>

// ---------------- types & helpers ----------------
typedef short short8 __attribute__((ext_vector_type(8)));
typedef float f32x4 __attribute__((ext_vector_type(4)));
static_assert(sizeof(short8) == 16, "short8 must be 16B");

#define DEVFN static __device__ __forceinline__

DEVFN unsigned short f2bf_rne(float f) {
    union { float f; unsigned u; } x; x.f = f;
    unsigned u = x.u + 0x7FFFu + ((x.u >> 16) & 1u);
    return (unsigned short)(u >> 16);
}
DEVFN float bf2f(unsigned short h) {
    union { unsigned u; float f; } x; x.u = ((unsigned)h) << 16;
    return x.f;
}
DEVFN void f2bf_split(float f, unsigned short& hi, unsigned short& lo) {
    hi = f2bf_rne(f);
    lo = f2bf_rne(f - bf2f(hi));
}
DEVFN void split8(const float4 a, const float4 b, short8& hi, short8& lo) {
    float v[8] = {a.x, a.y, a.z, a.w, b.x, b.y, b.z, b.w};
#pragma unroll
    for (int i = 0; i < 8; i++) {
        unsigned short h, l;
        f2bf_split(v[i], h, l);
        hi[i] = (short)h; lo[i] = (short)l;
    }
}
DEVFN f32x4 mfma16(short8 a, short8 b, f32x4 c) {
    return __builtin_amdgcn_mfma_f32_16x16x32_bf16(a, b, c, 0, 0, 0);
}
DEVFN float sigmoidf_(float x) { return 1.0f / (1.0f + expf(-x)); }

// fence-free poll: relaxed agent-scope atomic load bypasses L1/L2 (always fresh)
DEVFN void wait_flag(const unsigned* p, unsigned target) {
    while (__hip_atomic_load(p, __ATOMIC_RELAXED, __HIP_MEMORY_SCOPE_AGENT) < target)
        __builtin_amdgcn_s_sleep(1);
    __atomic_signal_fence(__ATOMIC_SEQ_CST);
}
// relaxed agent-scope atomic store: write-through to (coherent) Infinity Cache, no fence
DEVFN void put_u32(unsigned short* base, int idx, unsigned w) {
    __hip_atomic_store((unsigned*)(base + idx), w, __ATOMIC_RELAXED, __HIP_MEMORY_SCOPE_AGENT);
}

// ---------------- constants ----------------
#define BB 16
#define TT 128
#define VV 32000
#define HH 512
#define LL 2
#define DDOCS 8
#define AH 256
#define EOS_ID 3
#define NROWS (BB * TT)       // 2048 GEMM rows
#define NBLKS 250             // 32000/128 N panels

// workspace offsets
#define OFF_CTX      ((size_t)0x0)       // 64KB  ctx[B][L][H] f32
#define OFF_SCORES   ((size_t)0x10000)   // scores[B*D*L] f32
#define OFF_RAWID    ((size_t)0x11000)   // 2048 int
#define OFF_FE       ((size_t)0x13000)   // 16 int
#define OFF_BAR      ((size_t)0x14000)   // cnt0[128] + cnt1[128] u32 (memset 0)
#define OFF_XTOP_HI  ((size_t)0x100000)  // 2048*512 u16
#define OFF_XTOP_LO  ((size_t)0x300000)
#define OFF_PM       ((size_t)0x500000)  // 2048*250 f32 partial max
#define OFF_PS       ((size_t)0x700000)  // partial sumexp
#define OFF_PI       ((size_t)0x900000)  // partial argmax (int)
#define OFF_FACTOR   ((size_t)0xB00000)  // 2048*250 f32

// d_out scratch (region dead before c1 writes probs over it)
#define DOFF_XEMB_HI ((size_t)0x0)        // 2048*512 u16
#define DOFF_XEMB_LO ((size_t)0x200000)
#define DOFF_H0_HI   ((size_t)0x400000)   // raw h0 per t
#define DOFF_H0_LO   ((size_t)0x600000)
#define DOFF_H0M_HI  ((size_t)0x800000)   // mixed h0, 129 slots
#define DOFF_H0M_LO  ((size_t)0xA80000)
#define DOFF_H1M_HI  ((size_t)0xD00000)
#define DOFF_H1M_LO  ((size_t)0xF80000)

// ---------------- K0a: attention scores ----------------
__global__ void k0a_scores(const float* __restrict__ emb, const float* __restrict__ W1,
                           const float* __restrict__ b1, const float* __restrict__ W2,
                           const float* __restrict__ b2, float* __restrict__ scores) {
    int bid = blockIdx.x;  // (b*8+d)*2+l, 256
    int tid = threadIdx.x;
    __shared__ float sv[HH];
    const float* v = emb + (size_t)bid * HH;
    sv[tid] = v[tid]; sv[tid + 256] = v[tid + 256];
    __syncthreads();
    const float4* w4 = (const float4*)(W1 + (size_t)tid * HH);
    float s = b1[tid];
#pragma unroll 8
    for (int k = 0; k < HH / 4; k++) {
        float4 w = w4[k];
        s += w.x * sv[4 * k] + w.y * sv[4 * k + 1] + w.z * sv[4 * k + 2] + w.w * sv[4 * k + 3];
    }
    float t = tanhf(s) * W2[tid];
    __shared__ float red[256];
    red[tid] = t; __syncthreads();
    for (int off = 128; off > 0; off >>= 1) {
        if (tid < off) red[tid] += red[tid + off];
        __syncthreads();
    }
    if (tid == 0) scores[bid] = red[0] + b2[0];
}

// ---------------- K0b: softmax over docs + context ----------------
__global__ void k0b_ctx(const float* __restrict__ emb, const float* __restrict__ scores,
                        float* __restrict__ ctx) {
    int bid = blockIdx.x;  // b*2+l, 32
    int b = bid >> 1, l = bid & 1;
    int tid = threadIdx.x;
    float sc[DDOCS];
    float mx = -1e30f;
#pragma unroll
    for (int d = 0; d < DDOCS; d++) { sc[d] = scores[(b * DDOCS + d) * LL + l]; mx = fmaxf(mx, sc[d]); }
    float sum = 0.f;
#pragma unroll
    for (int d = 0; d < DDOCS; d++) { sc[d] = expf(sc[d] - mx); sum += sc[d]; }
    float inv = 1.0f / sum;
    for (int h = tid; h < HH; h += 256) {
        float acc = 0.f;
#pragma unroll
        for (int d = 0; d < DDOCS; d++)
            acc += sc[d] * inv * emb[((size_t)(b * DDOCS + d) * LL + l) * HH + h];
        ctx[(size_t)(b * LL + l) * HH + h] = acc;
    }
}

// ---------------- K1: embedding gather -> bf16 hi/lo ----------------
__global__ void k1_embed(const int* __restrict__ init_input, const int* __restrict__ targets,
                         const float* __restrict__ embW,
                         unsigned short* __restrict__ xe_hi, unsigned short* __restrict__ xe_lo) {
    int r = blockIdx.x;  // t*16+b
    int t = r >> 4, b = r & 15;
    int tok = (t == 0) ? init_input[b] : targets[b * TT + (t - 1)];
    const float* src = embW + (size_t)tok * HH;
    int tid = threadIdx.x;
    for (int k = tid; k < HH; k += 256) {
        unsigned short hi, lo;
        f2bf_split(src[k], hi, lo);
        xe_hi[(size_t)r * HH + k] = hi;
        xe_lo[(size_t)r * HH + k] = lo;
    }
}

// ---------------- K1b: init mixed hidden slot0 ----------------
__global__ void k1b_init(const float* __restrict__ ctx, const float* __restrict__ init_hidden,
                         unsigned short* __restrict__ h0m_hi, unsigned short* __restrict__ h0m_lo,
                         unsigned short* __restrict__ h1m_hi, unsigned short* __restrict__ h1m_lo) {
    int i = blockIdx.x * 256 + threadIdx.x;  // 0..16383
    if (i >= LL * BB * HH) return;
    int h = i & (HH - 1); int b = (i >> 9) & 15; int l = i >> 13;
    float c = ctx[(size_t)(b * LL + l) * HH + h];
    float ih = init_hidden[(size_t)(b * LL + l) * HH + h];
    float m = 0.5f * c + 0.5f * ih;
    unsigned short hi, lo; f2bf_split(m, hi, lo);
    size_t o = (size_t)b * HH + h;  // slot 0
    if (l == 0) { h0m_hi[o] = hi; h0m_lo[o] = lo; }
    else        { h1m_hi[o] = hi; h1m_lo[o] = lo; }
}

// ---------------- K2: persistent pipelined LSTM (fence-free flag sync) ----------------
// 128 blocks: 0..63 layer0, 64..127 layer1. Weights in VGPRs.
// Cross-block h values: relaxed agent-scope atomic u32 stores (write-through to
// coherent LLC, no L2 writeback); per-(layer,t) counters signal readiness.
// Consumers read with NORMAL cached loads — safe because each t-slot's lines are
// never touched before its flag trips (miss fetches the fresh LLC copy).
__global__ void __launch_bounds__(256, 1) k2_lstm(
    const float* __restrict__ W_ih, const float* __restrict__ W_hh,
    const float* __restrict__ b_ih, const float* __restrict__ b_hh,
    const float* __restrict__ ctx, const float* __restrict__ init_cell,
    const unsigned short* __restrict__ xe_hi, const unsigned short* __restrict__ xe_lo,
    unsigned short* __restrict__ h0_hi, unsigned short* __restrict__ h0_lo,
    unsigned short* __restrict__ h0m_hi, unsigned short* __restrict__ h0m_lo,
    unsigned short* __restrict__ h1m_hi, unsigned short* __restrict__ h1m_lo,
    unsigned short* __restrict__ xtop_hi, unsigned short* __restrict__ xtop_lo,
    unsigned int* __restrict__ cnt0, unsigned int* __restrict__ cnt1) {
    const int wg = blockIdx.x;
    const int layer = wg >> 6;
    const int j0 = (wg & 63) * 8;
    const int tid = threadIdx.x;
    const int wv = tid >> 6;
    const int lane = tid & 63;
    const int n16 = lane & 15, q = lane >> 4;
    const int klocal = (wv & 1) * 256 + q * 8;  // + ks*32 added per kstep

    // ---- load weight fragments into registers (bf16 hi/lo) ----
    short8 Wh[2][8], Wl[2][8];
    {
        const float* wb = (wv < 2) ? (W_ih + (size_t)layer * 2048 * 512)
                                   : (W_hh + (size_t)layer * 2048 * 512);
#pragma unroll
        for (int nt = 0; nt < 2; nt++) {
            int rl = nt * 16 + n16;
            int g = rl >> 3, j = rl & 7;
            int n = g * 512 + j0 + j;
#pragma unroll
            for (int ks = 0; ks < 8; ks++) {
                const float* src = wb + (size_t)n * 512 + klocal + ks * 32;
                float4 a = ((const float4*)src)[0];
                float4 b4 = ((const float4*)src)[1];
                split8(a, b4, Wh[nt][ks], Wl[nt][ks]);
            }
        }
    }
    // ---- reducer-thread persistent state ----
    int m_b = tid & 15, jj = tid >> 4;  // valid tid<128
    float ccell = 0.f, ctxv = 0.f, biasv[4] = {0, 0, 0, 0};
    if (tid < 128) {
#pragma unroll
        for (int g = 0; g < 4; g++) {
            int n = g * 512 + j0 + jj;
            biasv[g] = b_ih[layer * 2048 + n] + b_hh[layer * 2048 + n];
        }
        ccell = init_cell[(size_t)(m_b * LL + layer) * HH + j0 + jj];
        ctxv = ctx[(size_t)(m_b * LL + layer) * HH + j0 + jj];
    }

    __shared__ float part[4][32][16];  // [wave][row_local][batch]

    for (int t = 0; t < TT; t++) {
        // ---- per-wave dependency wait (only waves that consume dynamic data poll)
        const unsigned short* xbase_hi;
        const unsigned short* xbase_lo;
        if (layer == 0) {
            if (wv < 2) {
                xbase_hi = xe_hi + (size_t)t * 8192; xbase_lo = xe_lo + (size_t)t * 8192;
            } else {
                if (t > 0) wait_flag(&cnt0[t - 1], 64);
                xbase_hi = h0m_hi + (size_t)t * 8192; xbase_lo = h0m_lo + (size_t)t * 8192;
            }
        } else {
            if (wv < 2) {
                wait_flag(&cnt0[t], 64);
                xbase_hi = h0_hi + (size_t)t * 8192; xbase_lo = h0_lo + (size_t)t * 8192;
            } else {
                if (t > 0) wait_flag(&cnt1[t - 1], 64);
                xbase_hi = h1m_hi + (size_t)t * 8192; xbase_lo = h1m_lo + (size_t)t * 8192;
            }
        }
        const unsigned short* ah = xbase_hi + (size_t)n16 * 512 + klocal;
        const unsigned short* al = xbase_lo + (size_t)n16 * 512 + klocal;
        f32x4 acc0 = {0.f, 0.f, 0.f, 0.f}, acc1 = {0.f, 0.f, 0.f, 0.f};
#pragma unroll
        for (int ks = 0; ks < 8; ks++) {
            short8 Ah = *(const short8*)(ah + ks * 32);
            short8 Al = *(const short8*)(al + ks * 32);
            acc0 = mfma16(Ah, Wh[0][ks], acc0);
            acc0 = mfma16(Al, Wh[0][ks], acc0);
            acc0 = mfma16(Ah, Wl[0][ks], acc0);
            acc1 = mfma16(Ah, Wh[1][ks], acc1);
            acc1 = mfma16(Al, Wh[1][ks], acc1);
            acc1 = mfma16(Ah, Wl[1][ks], acc1);
        }
        // D[m=q*4+reg][col=n16] -> part[wv][rl][m]
#pragma unroll
        for (int reg = 0; reg < 4; reg++) {
            part[wv][n16][q * 4 + reg] = acc0[reg];
            part[wv][16 + n16][q * 4 + reg] = acc1[reg];
        }
        __syncthreads();
        if (tid < 128) {
            float gs[4];
#pragma unroll
            for (int g = 0; g < 4; g++) {
                int rl = g * 8 + jj;
                gs[g] = part[0][rl][m_b] + part[1][rl][m_b] + part[2][rl][m_b] +
                        part[3][rl][m_b] + biasv[g];
            }
            float ig = sigmoidf_(gs[0]), fg = sigmoidf_(gs[1]);
            float gg = tanhf(gs[2]), og = sigmoidf_(gs[3]);
            ccell = fg * ccell + ig * gg;
            float h = og * tanhf(ccell);
            float hm = 0.5f * ctxv + 0.5f * h;
            unsigned short hhi, hlo, mhi, mlo;
            f2bf_split(h, hhi, hlo);
            f2bf_split(hm, mhi, mlo);
            // pair adjacent-jj lanes (lane^16) -> packed u32 write-through stores
            unsigned p_hhi = (unsigned)__shfl_xor((int)(unsigned)hhi, 16);
            unsigned p_hlo = (unsigned)__shfl_xor((int)(unsigned)hlo, 16);
            unsigned p_mhi = (unsigned)__shfl_xor((int)(unsigned)mhi, 16);
            unsigned p_mlo = (unsigned)__shfl_xor((int)(unsigned)mlo, 16);
            int idx1 = (t * 16 + m_b) * 512 + j0 + jj;        // even jj only
            int idx2 = ((t + 1) * 16 + m_b) * 512 + j0 + jj;
            if ((jj & 1) == 0) {
                unsigned whh = (unsigned)hhi | (p_hhi << 16);
                unsigned whl = (unsigned)hlo | (p_hlo << 16);
                unsigned wmh = (unsigned)mhi | (p_mhi << 16);
                unsigned wml = (unsigned)mlo | (p_mlo << 16);
                if (layer == 0) {
                    put_u32(h0_hi, idx1, whh); put_u32(h0_lo, idx1, whl);
                    put_u32(h0m_hi, idx2, wmh); put_u32(h0m_lo, idx2, wml);
                } else {
                    put_u32(h1m_hi, idx2, wmh); put_u32(h1m_lo, idx2, wml);
                }
            }
            if (layer == 1) {  // xtop read by c1_gemm after kernel end: normal stores
                size_t o = (size_t)idx1;
                xtop_hi[o] = hhi; xtop_lo[o] = hlo;
            }
            // drain this wave's stores to the coherence point before the flag
            __atomic_signal_fence(__ATOMIC_SEQ_CST);
            __builtin_amdgcn_s_waitcnt(0);
            __atomic_signal_fence(__ATOMIC_SEQ_CST);
        }
        __syncthreads();  // all producer waves drained; part[] consumed
        if (tid == 0) {
            __hip_atomic_fetch_add(layer == 0 ? &cnt0[t] : &cnt1[t], 1u,
                                   __ATOMIC_RELAXED, __HIP_MEMORY_SCOPE_AGENT);
        }
    }
}

// ---------------- C1: logits GEMM (split-bf16 MFMA) + fused partial softmax ----------------
__global__ void __launch_bounds__(256, 2) c1_gemm(
    const unsigned short* __restrict__ xhi, const unsigned short* __restrict__ xlo,
    const float* __restrict__ Wout, const float* __restrict__ b_out,
    float* __restrict__ outp, float* __restrict__ pm, float* __restrict__ ps,
    int* __restrict__ pi) {
    const int M0 = blockIdx.x * 128;   // 16 M panels
    const int N0 = blockIdx.y * 128;   // 250 N panels
    const int tid = threadIdx.x;
    const int wv = tid >> 6;
    const int lane = tid & 63;
    const int n16 = lane & 15, q = lane >> 4;

    f32x4 acc[8][2];
#pragma unroll
    for (int mt = 0; mt < 8; mt++)
#pragma unroll
        for (int i = 0; i < 2; i++) acc[mt][i] = (f32x4){0.f, 0.f, 0.f, 0.f};

    for (int ks = 0; ks < 16; ks++) {
        short8 Bh[2], Bl[2];
#pragma unroll
        for (int i = 0; i < 2; i++) {
            int n = N0 + (wv * 2 + i) * 16 + n16;
            const float* src = Wout + (size_t)n * 512 + ks * 32 + q * 8;
            float4 f0 = ((const float4*)src)[0];
            float4 f1 = ((const float4*)src)[1];
            split8(f0, f1, Bh[i], Bl[i]);
        }
#pragma unroll
        for (int mt = 0; mt < 8; mt++) {
            size_t aoff = ((size_t)(M0 + mt * 16 + n16)) * 512 + ks * 32 + q * 8;
            short8 Ah = *(const short8*)(xhi + aoff);
            short8 Al = *(const short8*)(xlo + aoff);
#pragma unroll
            for (int i = 0; i < 2; i++) {
                acc[mt][i] = mfma16(Ah, Bh[i], acc[mt][i]);
                acc[mt][i] = mfma16(Al, Bh[i], acc[mt][i]);
                acc[mt][i] = mfma16(Ah, Bl[i], acc[mt][i]);
            }
        }
    }
    // epilogue: bias, per-row(128 col) max/argmax/sumexp, store exp(l - m_blk)
    int c0 = N0 + (wv * 2) * 16 + n16;
    int c1 = c0 + 16;
    float bo0 = b_out[c0], bo1 = b_out[c1];

    __shared__ float smax[4][128];
    __shared__ int sidx[4][128];
    __shared__ float ssum[4][128];
    __shared__ float fmax[128];
    __shared__ int fidx[128];

#pragma unroll
    for (int mt = 0; mt < 8; mt++) {
#pragma unroll
        for (int reg = 0; reg < 4; reg++) {
            float v0 = acc[mt][0][reg] + bo0;
            float v1 = acc[mt][1][reg] + bo1;
            acc[mt][0][reg] = v0; acc[mt][1][reg] = v1;
            float mv = v0; int mi = c0;
            if (v1 > mv) { mv = v1; mi = c1; }
#pragma unroll
            for (int d = 1; d < 16; d <<= 1) {
                float om = __shfl_xor(mv, d);
                int oi = __shfl_xor(mi, d);
                if (om > mv || (om == mv && oi < mi)) { mv = om; mi = oi; }
            }
            if (n16 == 0) {
                smax[wv][mt * 16 + q * 4 + reg] = mv;
                sidx[wv][mt * 16 + q * 4 + reg] = mi;
            }
        }
    }
    __syncthreads();
    if (tid < 128) {
        float M = smax[0][tid]; int I = sidx[0][tid];
#pragma unroll
        for (int w = 1; w < 4; w++) {
            float m2 = smax[w][tid]; int i2 = sidx[w][tid];
            if (m2 > M || (m2 == M && i2 < I)) { M = m2; I = i2; }
        }
        fmax[tid] = M; fidx[tid] = I;
    }
    __syncthreads();
#pragma unroll
    for (int mt = 0; mt < 8; mt++) {
#pragma unroll
        for (int reg = 0; reg < 4; reg++) {
            int row = mt * 16 + q * 4 + reg;
            float M = fmax[row];
            float e0 = __expf(acc[mt][0][reg] - M);
            float e1 = __expf(acc[mt][1][reg] - M);
            int rg = M0 + row;
            int t = rg >> 4, b = rg & 15;
            size_t base = ((size_t)b * TT + t) * VV;
            outp[base + c0] = e0;
            outp[base + c1] = e1;
            float s = e0 + e1;
#pragma unroll
            for (int d = 1; d < 16; d <<= 1) s += __shfl_xor(s, d);
            if (n16 == 0) ssum[wv][row] = s;
        }
    }
    __syncthreads();
    if (tid < 128) {
        float S = ssum[0][tid] + ssum[1][tid] + ssum[2][tid] + ssum[3][tid];
        size_t o = (size_t)(M0 + tid) * NBLKS + blockIdx.y;
        pm[o] = fmax[tid]; ps[o] = S; pi[o] = fidx[tid];
    }
}

// ---------------- C2: per-row stats + factors ----------------
__global__ void c2_rowstats(const float* __restrict__ pm, const float* __restrict__ ps,
                            const int* __restrict__ pi, float* __restrict__ factor,
                            int* __restrict__ raw_id) {
    int row = blockIdx.x;
    int tid = threadIdx.x;
    float mi = -1e30f, si = 0.f; int ii = 0x7FFFFFFF;
    if (tid < NBLKS) {
        size_t o = (size_t)row * NBLKS + tid;
        mi = pm[o]; si = ps[o]; ii = pi[o];
    }
    __shared__ float sm[256]; __shared__ int si_[256]; __shared__ float sv[256];
    sm[tid] = mi; si_[tid] = ii;
    __syncthreads();
    for (int off = 128; off > 0; off >>= 1) {
        if (tid < off) {
            float m2 = sm[tid + off]; int i2 = si_[tid + off];
            if (m2 > sm[tid] || (m2 == sm[tid] && i2 < si_[tid])) { sm[tid] = m2; si_[tid] = i2; }
        }
        __syncthreads();
    }
    float M = sm[0];
    float term = (tid < NBLKS) ? si * __expf(mi - M) : 0.f;
    sv[tid] = term;
    __syncthreads();
    for (int off = 128; off > 0; off >>= 1) {
        if (tid < off) sv[tid] += sv[tid + off];
        __syncthreads();
    }
    float S = sv[0];
    if (tid == 0) raw_id[row] = si_[0];
    if (tid < NBLKS) factor[(size_t)row * NBLKS + tid] = __expf(mi - M) / S;
}

// ---------------- C2b: eos scan + ids output ----------------
__global__ void c2b_ids(const int* __restrict__ raw_id, int* __restrict__ fe,
                        float* __restrict__ out_ids) {
    int tid = threadIdx.x;
    __shared__ int fes[BB];
    if (tid < BB) {
        int f = 1 << 30;
        for (int t = 0; t < TT; t++) {
            if (raw_id[t * 16 + tid] == EOS_ID) { f = t; break; }
        }
        fes[tid] = f;
        fe[tid] = f;
    }
    __syncthreads();
    for (int i = tid; i < NROWS; i += 256) {
        int b = i >> 7, t = i & 127;
        int id = (t > fes[b]) ? 0 : raw_id[t * 16 + b];
        out_ids[i] = (float)id;
    }
}

// ---------------- C3: in-place normalize / pad-mask ----------------
__global__ void c3_norm(float* __restrict__ outp, const float* __restrict__ factor,
                        const int* __restrict__ fe) {
    int rg = blockIdx.x;  // gemm row
    int t = rg >> 4, b = rg & 15;
    size_t base = ((size_t)b * TT + t) * VV;
    int tid = threadIdx.x;
    bool pad = t > fe[b];
    if (pad) {
        for (int i = tid; i < VV / 4; i += 256) {
            float4 v = {0.f, 0.f, 0.f, 0.f};
            if (i == 0) v.x = 1.0f;
            ((float4*)(outp + base))[i] = v;
        }
    } else {
        for (int i = tid; i < VV / 4; i += 256) {
            float4 p = ((float4*)(outp + base))[i];
            float f = factor[(size_t)rg * NBLKS + (i >> 5)];
            p.x *= f; p.y *= f; p.z *= f; p.w *= f;
            ((float4*)(outp + base))[i] = p;
        }
    }
}

// ---------------- launch ----------------
extern "C" void kernel_launch(void* const* d_in, const int* in_sizes, int n_in,
                              void* d_out, int out_size, void* d_ws, size_t ws_size,
                              hipStream_t stream) {
    const float* init_hidden = (const float*)d_in[0];
    const float* init_cell = (const float*)d_in[1];
    const int* init_input = (const int*)d_in[2];
    const int* targets = (const int*)d_in[3];
    const float* attend = (const float*)d_in[4];
    const float* embW = (const float*)d_in[5];
    const float* W_ih = (const float*)d_in[6];
    const float* W_hh = (const float*)d_in[7];
    const float* b_ih = (const float*)d_in[8];
    const float* b_hh = (const float*)d_in[9];
    const float* W_out = (const float*)d_in[10];
    const float* b_out = (const float*)d_in[11];
    const float* attn_W1 = (const float*)d_in[12];
    const float* attn_b1 = (const float*)d_in[13];
    const float* attn_W2 = (const float*)d_in[14];
    const float* attn_b2 = (const float*)d_in[15];

    char* ws = (char*)d_ws;
    float* ctx = (float*)(ws + OFF_CTX);
    float* scores = (float*)(ws + OFF_SCORES);
    int* raw_id = (int*)(ws + OFF_RAWID);
    int* fe = (int*)(ws + OFF_FE);
    unsigned int* cnt0 = (unsigned int*)(ws + OFF_BAR);
    unsigned int* cnt1 = cnt0 + 128;
    unsigned short* xtop_hi = (unsigned short*)(ws + OFF_XTOP_HI);
    unsigned short* xtop_lo = (unsigned short*)(ws + OFF_XTOP_LO);
    float* pm = (float*)(ws + OFF_PM);
    float* ps = (float*)(ws + OFF_PS);
    int* pi = (int*)(ws + OFF_PI);
    float* factor = (float*)(ws + OFF_FACTOR);

    char* dob = (char*)d_out;
    unsigned short* xe_hi = (unsigned short*)(dob + DOFF_XEMB_HI);
    unsigned short* xe_lo = (unsigned short*)(dob + DOFF_XEMB_LO);
    unsigned short* h0_hi = (unsigned short*)(dob + DOFF_H0_HI);
    unsigned short* h0_lo = (unsigned short*)(dob + DOFF_H0_LO);
    unsigned short* h0m_hi = (unsigned short*)(dob + DOFF_H0M_HI);
    unsigned short* h0m_lo = (unsigned short*)(dob + DOFF_H0M_LO);
    unsigned short* h1m_hi = (unsigned short*)(dob + DOFF_H1M_HI);
    unsigned short* h1m_lo = (unsigned short*)(dob + DOFF_H1M_LO);

    float* outp = (float*)d_out;
    float* out_ids = outp + (size_t)NROWS * VV;

    hipMemsetAsync(cnt0, 0, 256 * sizeof(unsigned int), stream);

    k0a_scores<<<256, 256, 0, stream>>>(attend, attn_W1, attn_b1, attn_W2, attn_b2, scores);
    k0b_ctx<<<32, 256, 0, stream>>>(attend, scores, ctx);
    k1_embed<<<NROWS, 256, 0, stream>>>(init_input, targets, embW, xe_hi, xe_lo);
    k1b_init<<<64, 256, 0, stream>>>(ctx, init_hidden, h0m_hi, h0m_lo, h1m_hi, h1m_lo);
    k2_lstm<<<128, 256, 0, stream>>>(W_ih, W_hh, b_ih, b_hh, ctx, init_cell,
                                     xe_hi, xe_lo, h0_hi, h0_lo, h0m_hi, h0m_lo,
                                     h1m_hi, h1m_lo, xtop_hi, xtop_lo, cnt0, cnt1);
    c1_gemm<<<dim3(16, NBLKS), 256, 0, stream>>>(xtop_hi, xtop_lo, W_out, b_out,
                                                 outp, pm, ps, pi);
    c2_rowstats<<<NROWS, 256, 0, stream>>>(pm, ps, pi, factor, raw_id);
    c2b_ids<<<1, 256, 0, stream>>>(raw_id, fe, out_ids);
    c3_norm<<<NROWS, 256, 0, stream>>>(outp, factor, fe);
}